// Round 8
// baseline (692.145 us; speedup 1.0000x reference)
//
#include <hip/hip_runtime.h>
#include <hip/hip_fp16.h>
#include <utility>
#include <type_traits>

// =====================================================================
// 16-qubit, batch-256 statevector simulator.  R8 architecture:
//
//  * one workgroup (1024 threads) per batch element; 64 amps/thread,
//    SPLIT: 32 in registers (h=0) + 32 in a 128 KB LDS array (h=1),
//    because the toolchain pins 1024-thread kernels to a 64-VGPR budget
//    (proven R2-R7: every attribute to raise it was ignored; S[64] in
//    regs spilled ~100 MB/dispatch scratch churn at 336 us).
//  * CNOT rings virtualized into GF(2) storage maps (rings free; gates
//    become pair updates j <-> j^m with role parity(c&j)).
//  * physical index j = [r:5][h:1][lane:6][wave:4].  Gate taxonomy:
//      - m thread-local            -> reg pairs + own-slice LDS pairs
//      - m has h                   -> reg <-> partner-LDS direct pairs
//                                     (works across waves! no staging)
//      - m lane-only, no h         -> shfl (reg half) + LDS owner pairs
//      - m wave-crossing, no h     -> BAD: staged exchange (reg half)
//    A constexpr greedy search chooses which stored bit plays h and
//    which 4 play wave, minimizing BAD-gate count.
//  * one __syncthreads per cross-thread gate (single-owner-per-word
//    protocol needs no intra-gate barriers); staging adds 16/bad gate.
// =====================================================================

// ---------------- compile-time GF(2) matrices ----------------
struct M16 { unsigned r[16]; };

constexpr M16 ident() { M16 m{}; for (int i = 0; i < 16; ++i) m.r[i] = 1u << i; return m; }

constexpr M16 ringm(int s) {
  M16 m = ident();
  for (int i = 15; i >= 0; --i) {
    int pc = 15 - i;
    int pt = 15 - ((i + s) & 15);
    m.r[pt] ^= m.r[pc];
  }
  return m;
}

constexpr M16 mmul(M16 A, M16 B) {
  M16 C{};
  for (int p = 0; p < 16; ++p) {
    unsigned v = 0;
    for (int q = 0; q < 16; ++q) if ((A.r[p] >> q) & 1u) v ^= B.r[q];
    C.r[p] = v;
  }
  return C;
}

constexpr M16 minv(M16 A) {
  M16 I = ident();
  for (int col = 0; col < 16; ++col) {
    int piv = -1;
    for (int row = col; row < 16; ++row) if ((A.r[row] >> col) & 1u) { piv = row; break; }
    unsigned t = A.r[piv]; A.r[piv] = A.r[col]; A.r[col] = t;
    t = I.r[piv]; I.r[piv] = I.r[col]; I.r[col] = t;
    for (int row = 0; row < 16; ++row)
      if (row != col && ((A.r[row] >> col) & 1u)) { A.r[row] ^= A.r[col]; I.r[row] ^= I.r[col]; }
  }
  return I;
}

constexpr bool meq(M16 a, M16 b) { for (int i = 0; i < 16; ++i) if (a.r[i] != b.r[i]) return false; return true; }
constexpr unsigned colmask(M16 P, int b) { unsigned m = 0; for (int p = 0; p < 16; ++p) m |= ((P.r[p] >> b) & 1u) << p; return m; }
constexpr int popc16(unsigned x) { int c = 0; for (int i = 0; i < 16; ++i) c += (x >> i) & 1; return c; }
constexpr int topbit_pow(unsigned x) { int b = 0; for (int i = 0; i < 16; ++i) if ((x >> i) & 1) b = i; return 1 << b; }
constexpr int ctzu(unsigned x) { for (int i = 0; i < 32; ++i) if ((x >> i) & 1) return i; return 32; }

struct Tables { unsigned gm[64]; unsigned gc[64]; unsigned meas[16]; };

constexpr Tables make_tables() {
  Tables T{};
  M16 R1 = ringm(1), R2 = ringm(2);
  M16 P0 = R1;
  M16 P1 = mmul(R1, R1);
  M16 P2 = mmul(P1, R2);
  M16 P3 = mmul(P2, R2);
  M16 P[4] = { P0, P1, P2, P3 };
  for (int k = 0; k < 4; ++k) {
    M16 A = minv(P[k]);
    for (int b = 0; b < 16; ++b) {
      T.gm[k * 16 + b] = colmask(P[k], b);  // pair mask (stored-index XOR)
      T.gc[k * 16 + b] = A.r[b];            // role/sign mask
    }
  }
  M16 A5 = minv(P[3]);
  for (int w = 0; w < 16; ++w) T.meas[w] = A5.r[15 - w];
  return T;
}

constexpr Tables TB = make_tables();

constexpr bool check_tables() {
  for (int g = 0; g < 64; ++g) if ((popc16(TB.gm[g] & TB.gc[g]) & 1) != 1) return false;
  if (!meq(mmul(ringm(1), minv(ringm(1))), ident())) return false;
  if (!meq(mmul(ringm(2), minv(ringm(2))), ident())) return false;
  return true;
}
static_assert(check_tables(), "GF(2) table inconsistency");
static_assert(sizeof(__half2) == 4, "half2 size");

// ---------------- bit-role assignment (constexpr greedy search) ------
// Choose h position + 4 wave positions minimizing gates with
// (mask ∩ wave != 0) && (h ∉ mask); then 5 r-positions maximizing
// fully-local gates.  Apply the resulting bit permutation to all
// masks/roles/measurement masks; init uses the inverse map.
struct Assign {
  int hpos; unsigned wset, rset, lset;
  int nbad;
  int phys_of[16];   // original stored-bit pos -> physical pos
  int orig_of[16];   // physical pos -> original stored-bit pos
  unsigned pm[64], pc[64], pmeas[16];
};

constexpr Assign make_assign() {
  Assign A{};
  int bestBad = 1000, bh = -1; unsigned bw = 0;
  for (int h = 0; h < 16; ++h) {
    // greedy 4-position cover of masks lacking h
    bool alive[64]; int nAlive = 0;
    for (int g = 0; g < 64; ++g) {
      alive[g] = ((TB.gm[g] >> h) & 1u) == 0u;
      if (alive[g]) ++nAlive;
    }
    unsigned w = 0;
    int covered = 0;
    for (int pick = 0; pick < 4; ++pick) {
      int bestP = -1, bestC = -1;
      for (int p = 0; p < 16; ++p) {
        if (p == h || ((w >> p) & 1u)) continue;
        int cnt = 0;
        for (int g = 0; g < 64; ++g)
          if (alive[g] && ((TB.gm[g] >> p) & 1u)) ++cnt;
        if (cnt > bestC) { bestC = cnt; bestP = p; }
      }
      w |= 1u << bestP;
      for (int g = 0; g < 64; ++g)
        if (alive[g] && ((TB.gm[g] >> bestP) & 1u)) { alive[g] = false; ++covered; }
    }
    int bad = covered;   // masks lacking h that intersect w
    if (bad < bestBad) { bestBad = bad; bh = h; bw = w; }
  }
  A.hpos = bh; A.wset = bw; A.nbad = bestBad;

  unsigned rem = 0xFFFFu & ~bw & ~(1u << bh);
  int pos[11] = {}; int np = 0;
  for (int p = 0; p < 16; ++p) if ((rem >> p) & 1u) pos[np++] = p;
  int bestLoc = -1; unsigned br = 0;
  for (int a = 0; a < 11; ++a) for (int b = a + 1; b < 11; ++b)
    for (int c = b + 1; c < 11; ++c) for (int d = c + 1; d < 11; ++d)
      for (int e = d + 1; e < 11; ++e) {
        unsigned r = (1u << pos[a]) | (1u << pos[b]) | (1u << pos[c]) | (1u << pos[d]) | (1u << pos[e]);
        unsigned localset = r | (1u << bh);
        int loc = 0;
        for (int g = 0; g < 64; ++g) if ((TB.gm[g] & ~localset) == 0u) ++loc;
        if (loc > bestLoc) { bestLoc = loc; br = r; }
      }
  A.rset = br; A.lset = rem & ~br;

  int pr = 0, pl = 6, pw = 12;
  for (int p = 0; p < 16; ++p) {
    if ((A.rset >> p) & 1u)      { A.phys_of[p] = pr;  A.orig_of[pr]  = p; ++pr; }
    else if (p == bh)            { A.phys_of[p] = 5;   A.orig_of[5]   = p; }
    else if ((A.lset >> p) & 1u) { A.phys_of[p] = pl;  A.orig_of[pl]  = p; ++pl; }
    else                         { A.phys_of[p] = pw;  A.orig_of[pw]  = p; ++pw; }
  }
  for (int g = 0; g < 64; ++g) {
    unsigned m = 0, c = 0;
    for (int p = 0; p < 16; ++p) {
      if ((TB.gm[g] >> p) & 1u) m |= 1u << A.phys_of[p];
      if ((TB.gc[g] >> p) & 1u) c |= 1u << A.phys_of[p];
    }
    A.pm[g] = m; A.pc[g] = c;
  }
  for (int w2 = 0; w2 < 16; ++w2) {
    unsigned mm = 0;
    for (int p = 0; p < 16; ++p) if ((TB.meas[w2] >> p) & 1u) mm |= 1u << A.phys_of[p];
    A.pmeas[w2] = mm;
  }
  return A;
}

constexpr Assign AS = make_assign();

constexpr bool check_assign() {
  for (int g = 0; g < 64; ++g) if ((popc16(AS.pm[g] & AS.pc[g]) & 1) != 1) return false;
  if (popc16(AS.rset) != 5 || popc16(AS.wset) != 4 || popc16(AS.lset) != 6) return false;
  return true;
}
static_assert(check_assign(), "assignment inconsistency");

// staging plan for BAD gates: 8 groups x 4 rows, closed under r -> r^mr
struct RPlan { int stage[32]; int slot[32]; };
constexpr RPlan make_rplan(unsigned mr) {
  RPlan P{}; bool vis[32] = {};
  int g = 0, sl = 0;
  for (int r = 0; r < 32; ++r) if (!vis[r]) {
    int p = r ^ (int)mr;
    P.stage[r] = g; P.slot[r] = sl; vis[r] = true; ++sl;
    if (p != r) { P.stage[p] = g; P.slot[p] = sl; vis[p] = true; ++sl; }
    if (sl >= 4) { sl = 0; ++g; }
  }
  return P;
}
template<unsigned MR> constexpr RPlan rplan_v = make_rplan(MR);

// ---------------- small device helpers ----------------
template<int N, int I = 0, typename F>
__device__ __forceinline__ void sfor(F&& f) {
  if constexpr (I < N) {
    f(std::integral_constant<int, I>{});
    sfor<N, I + 1>(static_cast<F&&>(f));
  }
}

__device__ __forceinline__ int h2i(__half2 v) { return __builtin_bit_cast(int, v); }
__device__ __forceinline__ __half2 i2h(int v) { return __builtin_bit_cast(__half2, v); }
__device__ __forceinline__ unsigned h2u(__half2 v) { return __builtin_bit_cast(unsigned, v); }
__device__ __forceinline__ __half2 u2h(unsigned v) { return __builtin_bit_cast(__half2, v); }

__device__ __forceinline__ __half2 hswap(__half2 v) { __half2 r; r.x = v.y; r.y = v.x; return r; }

// role-0: y = s0*x + s1*sw(x) + s2*xp + s3*sw(xp)
// role-1 = same with s1,s2 negated (sigma relation; free VOP3 neg mods)
template<int T>
__device__ __forceinline__ __half2 upd(__half2 x, __half2 xp, const __half2 (&s)[4]) {
  __half2 y = __hmul2(s[0], x);
  if constexpr (T) {
    y = __hfma2(__hneg2(s[1]), hswap(x), y);
    y = __hfma2(__hneg2(s[2]), xp, y);
  } else {
    y = __hfma2(s[1], hswap(x), y);
    y = __hfma2(s[2], xp, y);
  }
  y = __hfma2(s[3], hswap(xp), y);
  return y;
}

// SU(2) for U = Ry(c) Rz(b) Ry(a):  U = [[al, -conj(be)], [be, conj(al)]]
__device__ __forceinline__ void su2_coeffs(float a, float b, float c,
                                           float& are, float& aim, float& bre, float& bim) {
  float sapc, capc, samc, camc, sb, cb;
  __sincosf((a + c) * 0.5f, &sapc, &capc);
  __sincosf((a - c) * 0.5f, &samc, &camc);
  __sincosf(b * 0.5f, &sb, &cb);
  are = cb * capc;
  aim = -sb * camc;
  bre = cb * sapc;
  bim = sb * samc;
}

__device__ __forceinline__ unsigned pkh2(float lo, float hi) {
  return h2u(__floats2half2_rn(lo, hi));
}

__device__ __forceinline__ float2 cmulf(float2 a, float vr, float vi) {
  return make_float2(a.x * vr - a.y * vi, a.x * vi + a.y * vr);
}

// ---------------- generalized gate application ----------------
// physical j = r | h<<5 | tid<<6.  R[r] holds (r,h=0); ldsS[r*1024+tid]
// holds (r,h=1).  Coefficient tables pre-signed by f = parity(ct&tid),
// so template role index = local parity only.
template<int G>
__device__ __forceinline__ void apply_gate(__half2 (&R)[32], unsigned tid,
                                           const unsigned* ctab, unsigned* ldsS,
                                           unsigned* xbuf) {
  constexpr unsigned m   = AS.pm[G];
  constexpr unsigned c   = AS.pc[G];
  constexpr unsigned mr  = m & 31u;
  constexpr unsigned mh  = (m >> 5) & 1u;
  constexpr unsigned mt  = (m >> 6) & 1023u;
  constexpr unsigned mw  = m >> 12;
  constexpr unsigned cr  = c & 31u;
  constexpr unsigned chb = (c >> 5) & 1u;

  const unsigned f  = __popc((c >> 6) & tid) & 1u;
  const unsigned fm = f ? 0x80008000u : 0u;
  __half2 s[4];
  s[0] = u2h(ctab[G * 4 + 0]);
  s[1] = u2h(ctab[G * 4 + 1] ^ fm);
  s[2] = u2h(ctab[G * 4 + 2] ^ fm);
  s[3] = u2h(ctab[G * 4 + 3]);

  // barrier: order this gate's cross-thread LDS access against the
  // previous gate's writes.  Elided between consecutive thread-local
  // gates (they touch only their own slice).
  constexpr bool curLocal  = (m >> 6) == 0u;
  constexpr bool prevLocal = (G == 0) ? true : ((AS.pm[G - 1] >> 6) == 0u);
  if constexpr (!(curLocal && prevLocal)) __syncthreads();

  if constexpr (mt == 0u) {
    if constexpr (mh == 0u) {
      // ---- thread-local: reg pairs + own-slice LDS pairs ----
      constexpr int hb = topbit_pow(mr);
      sfor<16>([&](auto ii) {
        constexpr int i  = decltype(ii)::value;
        constexpr int r0 = ((i & ~(hb - 1)) << 1) | (i & (hb - 1));
        constexpr int r1 = r0 ^ (int)mr;
        constexpr int t0 = popc16(cr & (unsigned)r0) & 1;
        {
          const __half2 x0 = R[r0], x1 = R[r1];
          R[r0] = upd<t0>(x0, x1, s);
          R[r1] = upd<t0 ^ 1>(x1, x0, s);
        }
        {
          constexpr int tl = t0 ^ (int)chb;
          const __half2 x0 = u2h(ldsS[r0 * 1024 + tid]);
          const __half2 x1 = u2h(ldsS[r1 * 1024 + tid]);
          ldsS[r0 * 1024 + tid] = h2u(upd<tl>(x0, x1, s));
          ldsS[r1 * 1024 + tid] = h2u(upd<tl ^ 1>(x1, x0, s));
        }
      });
    } else {
      // ---- thread-local h gate: reg r <-> own LDS (r^mr) ----
      sfor<32>([&](auto rr) {
        constexpr int r = decltype(rr)::value;
        constexpr int t = popc16(cr & (unsigned)r) & 1;
        const __half2 x = R[r];
        const __half2 y = u2h(ldsS[(r ^ (int)mr) * 1024 + tid]);
        R[r] = upd<t>(x, y, s);
        ldsS[(r ^ (int)mr) * 1024 + tid] = h2u(upd<t ^ 1>(y, x, s));
      });
    }
  } else if constexpr (mh == 1u) {
    // ---- cross-thread h gate: reg <-> partner LDS (any mt, incl wave)
    // each pair = my reg + partner slice word; I am sole accessor of
    // that word (its owner is me), so no staging and no intra-gate
    // barrier even across waves.
    const unsigned pt = tid ^ mt;
    sfor<32>([&](auto rr) {
      constexpr int r = decltype(rr)::value;
      constexpr int t = popc16(cr & (unsigned)r) & 1;
      const __half2 x = R[r];
      const __half2 y = u2h(ldsS[(r ^ (int)mr) * 1024 + pt]);
      R[r] = upd<t>(x, y, s);
      ldsS[(r ^ (int)mr) * 1024 + pt] = h2u(upd<t ^ 1>(y, x, s));
    });
  } else {
    // ---- mh==0, cross-thread: LDS half owner-protocol + reg half ----
    const unsigned pt = tid ^ mt;
    // LDS half: pairs {(tid,r),(pt,r^mr)}, single owner per word.
    if constexpr (mr != 0u) {
      constexpr int q = ctzu(mr);            // owner iff bit q of r == 0
      sfor<32>([&](auto rr) {
        constexpr int r = decltype(rr)::value;
        if constexpr (((r >> q) & 1) == 0) {
          constexpr int r2 = r ^ (int)mr;
          constexpr int t  = (popc16(cr & (unsigned)r) & 1) ^ (int)chb;
          const __half2 x = u2h(ldsS[r * 1024 + tid]);
          const __half2 y = u2h(ldsS[r2 * 1024 + pt]);
          ldsS[r * 1024 + tid] = h2u(upd<t>(x, y, s));
          ldsS[r2 * 1024 + pt] = h2u(upd<t ^ 1>(y, x, s));
        }
      });
    } else {
      // same row both sides: balance ownership by row half vs tid bit
      const unsigned po = (tid >> ctzu(mt)) & 1u;
      sfor<32>([&](auto rr) {
        constexpr int r  = decltype(rr)::value;
        constexpr int r4 = (r >> 4) & 1;
        constexpr int t  = (popc16(cr & (unsigned)r) & 1) ^ (int)chb;
        if (po == (unsigned)r4) {
          const __half2 x = u2h(ldsS[r * 1024 + tid]);
          const __half2 y = u2h(ldsS[r * 1024 + pt]);
          ldsS[r * 1024 + tid] = h2u(upd<t>(x, y, s));
          ldsS[r * 1024 + pt]  = h2u(upd<t ^ 1>(y, x, s));
        }
      });
    }
    // reg half
    if constexpr (mw == 0u) {
      // lane-crossing: shfl
      if constexpr (mr == 0u) {
        sfor<32>([&](auto rr) {
          constexpr int r = decltype(rr)::value;
          constexpr int t = popc16(cr & (unsigned)r) & 1;
          const __half2 xp = i2h(__shfl_xor(h2i(R[r]), (int)mt, 64));
          R[r] = upd<t>(R[r], xp, s);
        });
      } else {
        constexpr int hb = topbit_pow(mr);
        constexpr int dt = popc16(cr & mr) & 1;
        sfor<16>([&](auto ii) {
          constexpr int i  = decltype(ii)::value;
          constexpr int r0 = ((i & ~(hb - 1)) << 1) | (i & (hb - 1));
          constexpr int r1 = r0 ^ (int)mr;
          constexpr int t  = popc16(cr & (unsigned)r0) & 1;
          const __half2 x0 = R[r0], x1 = R[r1];
          const __half2 xp0 = i2h(__shfl_xor(h2i(x1), (int)mt, 64));
          const __half2 xp1 = i2h(__shfl_xor(h2i(x0), (int)mt, 64));
          R[r0] = upd<t>(x0, xp0, s);
          R[r1] = upd<t ^ dt>(x1, xp1, s);
        });
      }
    } else {
      // BAD gate: wave-crossing reg<->reg; staged exchange, 4 rows/iter
      sfor<8>([&](auto gi) {
        constexpr int gidx = decltype(gi)::value;
        sfor<32>([&](auto rr) {
          constexpr int r = decltype(rr)::value;
          if constexpr (rplan_v<mr>.stage[r] == gidx)
            xbuf[rplan_v<mr>.slot[r] * 1024 + tid] = h2u(R[r]);
        });
        __syncthreads();
        sfor<32>([&](auto rr) {
          constexpr int r = decltype(rr)::value;
          if constexpr (rplan_v<mr>.stage[r] == gidx) {
            constexpr int t = popc16(cr & (unsigned)r) & 1;
            const __half2 xp = u2h(xbuf[rplan_v<mr>.slot[r ^ (int)mr] * 1024 + pt]);
            R[r] = upd<t>(R[r], xp, s);
          }
        });
        __syncthreads();
      });
    }
  }
}

// ---------------- main kernel ----------------
__global__ __launch_bounds__(1024)
void qcir_kernel(const float* __restrict__ inputs, const float* __restrict__ weight,
                 float* __restrict__ out) {
  __shared__ unsigned ldsS[32 * 1024];   // 128 KB: h=1 state half
  __shared__ unsigned xbuf[4 * 1024];    // 16 KB: staging for BAD gates
  __shared__ unsigned ctab[64 * 4];      // per-gate packed coeffs
  __shared__ float4   itab[16];          // per-wire (al,be) after enc+L1
  __shared__ float    red[16 * 16];      // reduction scratch

  const unsigned tid = threadIdx.x;
  const unsigned b   = blockIdx.x;

  // ---- coefficient tables ----
  if (tid < 64) {
    const int g  = (int)tid;
    const int k  = g >> 4;
    const int bb = g & 15;
    const int w  = 15 - bb;
    const int base = 48 * (k + 1) + 3 * w;
    float are, aim, bre, bim;
    su2_coeffs(weight[base], weight[base + 1], weight[base + 2], are, aim, bre, bim);
    ctab[g * 4 + 0] = pkh2(are, are);
    ctab[g * 4 + 1] = pkh2(-aim, aim);
    ctab[g * 4 + 2] = pkh2(-bre, -bre);
    ctab[g * 4 + 3] = pkh2(-bim, bim);
  } else if (tid < 80) {
    const int w = (int)tid - 64;
    const float a = weight[3 * w] + inputs[b * 16 + w];
    float are, aim, bre, bim;
    su2_coeffs(a, weight[3 * w + 1], weight[3 * w + 2], are, aim, bre, bim);
    itab[w] = make_float4(are, aim, bre, bim);
  }
  __syncthreads();

  // ---- init: product state after encoding + layer 1 (A1 = I) ----
  // stored physical bit pp corresponds to original stored bit
  // AS.orig_of[pp] = psi bit -> wire 15 - AS.orig_of[pp].
  __half2 R[32];
  float2 P0 = make_float2(1.f, 0.f);
#pragma unroll
  for (int pp = 6; pp < 16; ++pp) {
    const int bit = (int)(tid >> (pp - 6)) & 1;
    const float4 tt = itab[15 - AS.orig_of[pp]];
    P0 = cmulf(P0, bit ? tt.z : tt.x, bit ? tt.w : tt.y);
  }
  const float4 th = itab[15 - AS.orig_of[5]];
  const float2 Ph0 = cmulf(P0, th.x, th.y);
  const float2 Ph1 = cmulf(P0, th.z, th.w);
  sfor<32>([&](auto rr) {
    constexpr int r = decltype(rr)::value;
    float2 v0 = Ph0, v1 = Ph1;
    sfor<5>([&](auto qq) {
      constexpr int q   = decltype(qq)::value;
      constexpr int bit = (r >> q) & 1;
      const float4 tq = itab[15 - AS.orig_of[q]];
      if constexpr (bit) { v0 = cmulf(v0, tq.z, tq.w); v1 = cmulf(v1, tq.z, tq.w); }
      else               { v0 = cmulf(v0, tq.x, tq.y); v1 = cmulf(v1, tq.x, tq.y); }
    });
    R[r] = __floats2half2_rn(v0.x, v0.y);
    ldsS[r * 1024 + tid] = h2u(__floats2half2_rn(v1.x, v1.y));
  });

  // ---- layers 2..5: 64 generalized gates ----
  sfor<64>([&](auto gg) { apply_gate<decltype(gg)::value>(R, tid, ctab, ldsS, xbuf); });

  // ---- measurement: <Z_w> via signed probability sums ----
  __syncthreads();
  float acc[16];
  sfor<16>([&](auto ww) { acc[decltype(ww)::value] = 0.f; });
  sfor<32>([&](auto rr) {          // register half (h=0)
    constexpr int r = decltype(rr)::value;
    const float re = __low2float(R[r]);
    const float im = __high2float(R[r]);
    const float p = re * re + im * im;
    sfor<16>([&](auto ww) {
      constexpr int w = decltype(ww)::value;
      constexpr int t = popc16(AS.pmeas[w] & 31u & (unsigned)r) & 1;
      if constexpr (t) acc[w] -= p; else acc[w] += p;
    });
  });
  sfor<32>([&](auto rr) {          // LDS half (h=1)
    constexpr int r = decltype(rr)::value;
    const __half2 v = u2h(ldsS[r * 1024 + tid]);
    const float re = __low2float(v);
    const float im = __high2float(v);
    const float p = re * re + im * im;
    sfor<16>([&](auto ww) {
      constexpr int w = decltype(ww)::value;
      constexpr int t = (popc16(AS.pmeas[w] & 31u & (unsigned)r) & 1) ^
                        (int)((AS.pmeas[w] >> 5) & 1u);
      if constexpr (t) acc[w] -= p; else acc[w] += p;
    });
  });
  sfor<16>([&](auto ww) {
    constexpr int w = decltype(ww)::value;
    const unsigned fw = __popc((AS.pmeas[w] >> 6) & tid) & 1u;
    float z = fw ? -acc[w] : acc[w];
#pragma unroll
    for (int d = 1; d < 64; d <<= 1) z += __shfl_xor(z, d, 64);
    if ((tid & 63u) == 0u) red[(tid >> 6) * 16 + w] = z;
  });
  __syncthreads();
  if (tid < 16) {
    float sum = 0.f;
#pragma unroll
    for (int v = 0; v < 16; ++v) sum += red[v * 16 + tid];
    out[b * 16 + tid] = 4.f * sum;
  }
}

// ---------------- launcher ----------------
extern "C" void kernel_launch(void* const* d_in, const int* in_sizes, int n_in,
                              void* d_out, int out_size, void* d_ws, size_t ws_size,
                              hipStream_t stream) {
  const float* inputs = (const float*)d_in[0];   // (B, 16) f32
  const float* weight = (const float*)d_in[1];   // (240,)  f32
  float* out = (float*)d_out;                    // (B, 16) f32
  const int B = in_sizes[0] / 16;
  qcir_kernel<<<B, 1024, 0, stream>>>(inputs, weight, out);
}